// Round 1
// baseline (139.726 us; speedup 1.0000x reference)
//
#include <hip/hip_runtime.h>
#include <hip/hip_bf16.h>

#define NXC 440
#define NYC 500
#define GCELLS (NXC * NYC)              // 220000 (NZ = 1)
#define NWORDS ((GCELLS + 31) / 32)     // 6875 bitmap words
#define NWP 6876                        // NWORDS padded to %4 (uint4 init/flush)
#define MAXV 40000
#define MAXP 32
#define SCANB ((NWORDS + 255) / 256)    // 27 blocks for word-sliced kernels
#define GPB 16                          // bitmaps OR'd per k_orred block
#define TPAD 16                         // ticket stride (ints): 1 counter / 64B line
#define CELLG 256                       // k_cell blocks (1024 threads each)

// Expected outputs are bf16-quantized but stored as fp32: round-trip.
__device__ __forceinline__ float bf16r(float x) {
    return __bfloat162float(__float2bfloat16(x));
}

// Linear cell index exactly as the reference (fp32 ops). Invalid -> -1.
__device__ __forceinline__ int cell_of(float x, float y, float z) {
    bool valid = (x >= 0.0f) && (x < 70.4f) &&
                 (y >= -40.0f) && (y < 40.0f) &&
                 (z >= -3.0f) && (z < 1.0f);
    if (!valid) return -1;
    int cx = (int)floorf(x / 0.16f);
    int cy = (int)floorf((y + 40.0f) / 0.16f);
    // z in [-3,1) -> cz == 0 always (NZ = 1)
    cx = min(max(cx, 0), NXC - 1);
    cy = min(max(cy, 0), NYC - 1);
    return cy * NXC + cx;
}

// Pass 1: LDS occupancy bitmap + cellid cache + folded zero-init.
// 1024-thread blocks: 16 waves/CU (vs 8 before) and half the bitmap copies.
// Points loaded as 5x float4 per 4 points: fully coalesced 16B lanes.
__global__ __launch_bounds__(1024) void k_cell(const float* pts, int* cellid,
                                               unsigned* bitmaps, unsigned* occ,
                                               int* ticket, int n) {
    __shared__ unsigned bm[NWP];        // 27.5 KB
    {
        uint4* bm4 = (uint4*)bm;
        for (int w = threadIdx.x; w < NWP / 4; w += 1024)
            bm4[w] = make_uint4(0u, 0u, 0u, 0u);
    }
    __syncthreads();
    int tid = blockIdx.x * 1024 + threadIdx.x;
    int nq = n >> 2;                    // groups of 4 points
    int stride = CELLG * 1024;
    const float4* p4 = (const float4*)pts;
    for (int q = tid; q < nq; q += stride) {
        float4 f0 = p4[q * 5 + 0];      // floats 0..3   (pt0 xyzw0)
        float4 f1 = p4[q * 5 + 1];      // floats 4..7
        float4 f2 = p4[q * 5 + 2];      // floats 8..11
        float4 f3 = p4[q * 5 + 3];      // floats 12..15
        float4 f4 = p4[q * 5 + 4];      // floats 16..19
        int c0 = cell_of(f0.x, f0.y, f0.z);   // floats 0,1,2
        int c1 = cell_of(f1.y, f1.z, f1.w);   // floats 5,6,7
        int c2 = cell_of(f2.z, f2.w, f3.x);   // floats 10,11,12
        int c3 = cell_of(f3.w, f4.x, f4.y);   // floats 15,16,17
        if (cellid) ((int4*)cellid)[q] = make_int4(c0, c1, c2, c3);
        if (c0 >= 0) atomicOr(&bm[c0 >> 5], 1u << (c0 & 31));
        if (c1 >= 0) atomicOr(&bm[c1 >> 5], 1u << (c1 & 31));
        if (c2 >= 0) atomicOr(&bm[c2 >> 5], 1u << (c2 & 31));
        if (c3 >= 0) atomicOr(&bm[c3 >> 5], 1u << (c3 & 31));
    }
    // tail (n % 4 != 0): handled scalar by one thread into block 0's bitmap
    if (tid == 0) {
        for (int i = nq * 4; i < n; ++i) {
            const float* p = pts + (size_t)i * 5;
            int c = cell_of(p[0], p[1], p[2]);
            if (cellid) cellid[i] = c;
            if (c >= 0) atomicOr(&bm[c >> 5], 1u << (c & 31));
        }
    }
    // folded zero-init for later kernels (stream order guarantees visibility)
    for (int idx = tid; idx < NWP; idx += stride) occ[idx] = 0u;
    for (int idx = tid; idx < MAXV * TPAD; idx += stride) ticket[idx] = 0;
    __syncthreads();
    uint4* dst4 = (uint4*)(bitmaps + (size_t)blockIdx.x * NWP);
    const uint4* src4 = (const uint4*)bm;
    for (int w = threadIdx.x; w < NWP / 4; w += 1024) dst4[w] = src4[w];
}

// Parallel OR-reduce: block (bx, by) ORs bitmaps [by*GPB, (by+1)*GPB) over its
// 256-word slice, one atomicOr per nonzero word into occ (zeroed in k_cell).
__global__ __launch_bounds__(256) void k_orred(const unsigned* bitmaps, unsigned* occ) {
    int w = blockIdx.x * 256 + threadIdx.x;
    if (w >= NWORDS) return;
    const unsigned* src = bitmaps + (size_t)blockIdx.y * GPB * NWP + w;
    unsigned o = 0u;
    #pragma unroll
    for (int g = 0; g < GPB; ++g) o |= src[(size_t)g * NWP];
    if (o) atomicOr(&occ[w], o);
}

// Word-level exclusive scan (self-computed cross-block base: occ is 27.5 KB,
// L2-resident) -> fused (prefix, occword) int2 table; emit coords for kept voxels.
__global__ __launch_bounds__(256) void k_scan(const unsigned* occ,
                                              int2* wp2, float* out_coords) {
    int b = blockIdx.x, t = threadIdx.x;
    // cross-block base: popcount of all words before this block's slice (uint4)
    __shared__ int sb[256];
    int pre = 0;
    const uint4* occ4 = (const uint4*)occ;
    for (int i = t; i < b * 64; i += 256) {
        uint4 v = occ4[i];
        pre += __popc(v.x) + __popc(v.y) + __popc(v.z) + __popc(v.w);
    }
    sb[t] = pre;
    __syncthreads();
    for (int d = 128; d > 0; d >>= 1) {
        if (t < d) sb[t] += sb[t + d];
        __syncthreads();
    }
    int base = sb[0];
    // intra-block scan over this slice
    int w = b * 256 + t;
    unsigned o = (w < NWORDS) ? occ[w] : 0u;
    int c = __popc(o);
    __shared__ int s[256];
    s[t] = c;
    __syncthreads();
    for (int d = 1; d < 256; d <<= 1) {
        int v = (t >= d) ? s[t - d] : 0;
        __syncthreads();
        s[t] += v;
        __syncthreads();
    }
    int vid = base + (s[t] - c);
    if (w < NWORDS) {
        wp2[w] = make_int2(vid, (int)o);
        if (vid < MAXV) {
            unsigned m = o;
            while (m) {
                int bit = __ffs(m) - 1;
                m &= m - 1u;
                if (vid < MAXV) {
                    int cell = w * 32 + bit;
                    int cy = cell / NXC, cx = cell - cy * NXC;
                    float* oc = out_coords + (size_t)vid * 3;
                    oc[0] = 0.0f;
                    oc[1] = bf16r((float)cy);
                    oc[2] = bf16r((float)cx);
                }
                ++vid;
            }
        }
    }
}

__device__ __forceinline__ void scat1(int cell, int i, const int2* wp2,
                                      int* ticket, int* seg, int S) {
    if (cell < 0) return;
    int w = cell >> 5, b = cell & 31;
    int2 t2 = wp2[w];                   // one 8B L2 load (prefix + occ word)
    int vid = t2.x + __popc(((unsigned)t2.y) & ((1u << b) - 1u));
    if (vid >= MAXV) return;
    int t = atomicAdd(&ticket[(size_t)vid * TPAD], 1);
    if (t < S) seg[(size_t)vid * S + t] = i;
}

// Scatter point indices into fixed-stride per-voxel segments, 8 pts/thread
// via 2x int4 cellid loads (8 independent lookup->atomic chains: latency ILP).
__global__ __launch_bounds__(256) void k_scatter(const float* pts, const int* cellid,
                                                 const int2* wp2,
                                                 int* ticket, int* seg, int S, int n) {
    int g = blockIdx.x * 256 + threadIdx.x;
    int n8 = n >> 3;
    if (cellid) {
        if (g < n8) {
            const int4* c4 = (const int4*)cellid;
            int4 ca = c4[g * 2], cb = c4[g * 2 + 1];
            int i0 = g * 8;
            scat1(ca.x, i0 + 0, wp2, ticket, seg, S);
            scat1(ca.y, i0 + 1, wp2, ticket, seg, S);
            scat1(ca.z, i0 + 2, wp2, ticket, seg, S);
            scat1(ca.w, i0 + 3, wp2, ticket, seg, S);
            scat1(cb.x, i0 + 4, wp2, ticket, seg, S);
            scat1(cb.y, i0 + 5, wp2, ticket, seg, S);
            scat1(cb.z, i0 + 6, wp2, ticket, seg, S);
            scat1(cb.w, i0 + 7, wp2, ticket, seg, S);
        }
        if (g == 0) {
            for (int i = n8 * 8; i < n; ++i)
                scat1(cellid[i], i, wp2, ticket, seg, S);
        }
    } else {
        if (g < n) {
            const float* p = pts + (size_t)g * 5;
            scat1(cell_of(p[0], p[1], p[2]), g, wp2, ticket, seg, S);
        }
    }
}

// One wave per voxel: rank by original index (stable), gather feats, write ALL
// 32 slots (zeros for empty ranks) + num_points. No output memset needed.
__global__ __launch_bounds__(256) void k_fill(const float* pts, const int* ticket,
                                              const int* seg, int S,
                                              float* out_vox, float* out_np) {
    __shared__ int slot[4][MAXP];
    int wave = threadIdx.x >> 6, lane = threadIdx.x & 63;
    int v = blockIdx.x * 4 + wave;     // MAXV % 4 == 0 -> always in range
    int ntot = ticket[(size_t)v * TPAD];
    int nn = min(ntot, S);             // S >= 32; P(cell count > S) ~ 0
    int m = min(nn, MAXP);
    int myidx = (lane < nn) ? seg[(size_t)v * S + lane] : 0x7fffffff;
    int rank = 0;
    for (int j = 0; j < nn; ++j) {
        int ej = __shfl(myidx, j, 64);
        rank += (ej < myidx) ? 1 : 0;
    }
    if (lane < nn && rank < MAXP) slot[wave][rank] = myidx;
    __syncthreads();   // order LDS scatter before readback (all threads reach)
    if (lane < MAXP) {
        float* dst = out_vox + ((size_t)v * MAXP + lane) * 5;
        if (lane < m) {
            const float* src = pts + (size_t)slot[wave][lane] * 5;
            #pragma unroll
            for (int k = 0; k < 5; ++k) dst[k] = bf16r(src[k]);
        } else {
            #pragma unroll
            for (int k = 0; k < 5; ++k) dst[k] = 0.0f;
        }
    }
    if (lane == 0) out_np[v] = bf16r((float)m);
}

extern "C" void kernel_launch(void* const* d_in, const int* in_sizes, int n_in,
                              void* d_out, int out_size, void* d_ws, size_t ws_size,
                              hipStream_t stream) {
    const float* pts = (const float*)d_in[0];
    int n = in_sizes[0] / 5;

    float* out = (float*)d_out;   // fp32 storage, bf16-precision values
    float* out_vox    = out;                                   // MAXV*32*5
    float* out_coords = out + (size_t)MAXV * MAXP * 5;         // MAXV*3
    float* out_np     = out_coords + (size_t)MAXV * 3;         // MAXV

    // ws ints: cellid[ncid]? + bitmaps[CELLG*NWP] + occ[NWP] + ticket[MAXV*TPAD]
    //          + wp2[2*NWORDS] + seg[MAXV*S]
    size_t ws_ints = ws_size / sizeof(int);
    size_t ncid = ((size_t)n + 3) & ~(size_t)3;   // keep bitmaps 16B-aligned
    const size_t fixed = (size_t)CELLG * NWP + NWP + (size_t)MAXV * TPAD
                       + 2 * (size_t)NWORDS;
    int S = 32; bool use_cid = false;
    {
        auto fits = [&](int s, bool cid) {
            return fixed + (size_t)MAXV * s + (cid ? ncid : 0) <= ws_ints;
        };
        struct Cfg { int s; bool cid; };
        const Cfg cfgs[] = {
            {64, true}, {48, true}, {40, true},
            {64, false}, {48, false}, {32, false},
        };
        for (const Cfg& c : cfgs) {
            if (fits(c.s, c.cid)) { S = c.s; use_cid = c.cid; break; }
        }
    }

    int* ws = (int*)d_ws;
    int* cellid        = use_cid ? ws : nullptr;                       // ncid (optional)
    unsigned* bitmaps  = (unsigned*)(ws + (use_cid ? ncid : 0));       // CELLG*NWP
    unsigned* occ      = bitmaps + (size_t)CELLG * NWP;                // NWP (zeroed in k_cell)
    int* ticket        = (int*)(occ + NWP);                            // MAXV*TPAD (zeroed in k_cell)
    int2* wp2          = (int2*)(ticket + (size_t)MAXV * TPAD);        // NWORDS (8B-aligned)
    int* seg           = (int*)(wp2 + NWORDS);                         // MAXV * S

    int nb  = (n + 255) / 256;
    int nb8 = (n / 8 + 255) / 256;
    k_cell<<<CELLG, 1024, 0, stream>>>(pts, cellid, bitmaps, occ, ticket, n);
    k_orred<<<dim3(SCANB, CELLG / GPB), 256, 0, stream>>>(bitmaps, occ);
    k_scan<<<SCANB, 256, 0, stream>>>(occ, wp2, out_coords);
    k_scatter<<<(use_cid ? nb8 : nb), 256, 0, stream>>>(pts, cellid, wp2,
                                                        ticket, seg, S, n);
    k_fill<<<(MAXV + 3) / 4, 256, 0, stream>>>(pts, ticket, seg, S, out_vox, out_np);
}